// Round 7
// baseline (892.864 us; speedup 1.0000x reference)
//
#include <hip/hip_runtime.h>
#include <hip/hip_bf16.h>
#include <math.h>

#define NN 50000
#define NFEAT 256
#define NHID 64
#define NCLASS 40
#define EDGES 800000

// coarse buckets: 256 nodes per bucket -> 64KB LDS accumulator per block
#define BKT_SH 8
#define BKT_W (1 << BKT_SH)                   // 256
#define NBKT ((NN + BKT_W - 1) / BKT_W)       // 196
#define CAP 40                                // LDS bin capacity (lambda~21)
#define NBLK1 196
#define CHUNK1 ((EDGES + NBLK1 - 1) / NBLK1)  // 4082

// ---------------- GEMM1: xw = x @ W1  (f32 tiled, 64x64 tile, 4x4 microtile) ----
#define BM 64
#define BK 32
__global__ __launch_bounds__(256) void k_gemm1(const float* __restrict__ x,
                                               const float* __restrict__ W1,
                                               float* __restrict__ xw) {
    __shared__ float xs[BK][BM + 4];
    __shared__ float ws[BK][NHID];
    const int tid = threadIdx.x;
    const int tx  = tid & 15;
    const int ty  = tid >> 4;
    const int r0  = blockIdx.x * BM;

    float acc[4][4] = {};

    for (int kc = 0; kc < NFEAT; kc += BK) {
        #pragma unroll
        for (int p = 0; p < 2; ++p) {
            int e   = tid * 4 + p * 1024;
            int row = e >> 5;
            int k   = e & 31;
            int gr  = r0 + row;
            float4 v = make_float4(0.f, 0.f, 0.f, 0.f);
            if (gr < NN) v = *(const float4*)&x[(size_t)gr * NFEAT + kc + k];
            xs[k + 0][row] = v.x; xs[k + 1][row] = v.y;
            xs[k + 2][row] = v.z; xs[k + 3][row] = v.w;
        }
        #pragma unroll
        for (int p = 0; p < 2; ++p) {
            int e  = tid * 4 + p * 1024;
            int kk = e >> 6;
            int c  = e & 63;
            *(float4*)&ws[kk][c] = *(const float4*)&W1[(size_t)(kc + kk) * NHID + c];
        }
        __syncthreads();
        #pragma unroll
        for (int kk = 0; kk < BK; ++kk) {
            float4 a = *(const float4*)&xs[kk][ty * 4];
            float4 b = *(const float4*)&ws[kk][tx * 4];
            acc[0][0] += a.x * b.x; acc[0][1] += a.x * b.y; acc[0][2] += a.x * b.z; acc[0][3] += a.x * b.w;
            acc[1][0] += a.y * b.x; acc[1][1] += a.y * b.y; acc[1][2] += a.y * b.z; acc[1][3] += a.y * b.w;
            acc[2][0] += a.z * b.x; acc[2][1] += a.z * b.y; acc[2][2] += a.z * b.z; acc[2][3] += a.z * b.w;
            acc[3][0] += a.w * b.x; acc[3][1] += a.w * b.y; acc[3][2] += a.w * b.z; acc[3][3] += a.w * b.w;
        }
        __syncthreads();
    }
    #pragma unroll
    for (int i = 0; i < 4; ++i) {
        int gr = r0 + ty * 4 + i;
        if (gr < NN)
            *(float4*)&xw[(size_t)gr * NHID + tx * 4] =
                make_float4(acc[i][0], acc[i][1], acc[i][2], acc[i][3]);
    }
}

// ---------------- bucket histogram / scan / bin ----------------------------
__global__ void k_zero0(int* __restrict__ bcnt) {
    if (threadIdx.x < NBKT) bcnt[threadIdx.x] = 0;
}

// per-block LDS hist of coarse buckets, one global add per bucket per block
__global__ __launch_bounds__(256) void k_bhist(const int* __restrict__ dst,
                                               int* __restrict__ bcnt) {
    __shared__ int lh[NBKT];
    const int tid = threadIdx.x;
    for (int b = tid; b < NBKT; b += 256) lh[b] = 0;
    __syncthreads();
    int t = blockIdx.x * 256 + tid;
    if (t < EDGES / 4) {
        int4 d = ((const int4*)dst)[t];
        atomicAdd(&lh[d.x >> BKT_SH], 1);
        atomicAdd(&lh[d.y >> BKT_SH], 1);
        atomicAdd(&lh[d.z >> BKT_SH], 1);
        atomicAdd(&lh[d.w >> BKT_SH], 1);
    }
    __syncthreads();
    for (int b = tid; b < NBKT; b += 256) {
        int n = lh[b];
        if (n) atomicAdd(&bcnt[b], n);
    }
}

// single-block exclusive scan of 196 bucket counts
__global__ __launch_bounds__(256) void k_bscan(const int* __restrict__ bcnt,
                                               int* __restrict__ bbase,
                                               int* __restrict__ bcur) {
    __shared__ int s[256];
    const int tid = threadIdx.x;
    int v = (tid < NBKT) ? bcnt[tid] : 0;
    s[tid] = v;
    __syncthreads();
    for (int off = 1; off < 256; off <<= 1) {
        int t = (tid >= off) ? s[tid - off] : 0;
        __syncthreads();
        s[tid] += t;
        __syncthreads();
    }
    if (tid < NBKT) {
        int excl = s[tid] - v;
        bbase[tid] = excl;
        bcur[tid]  = excl;
    }
    if (tid == NBKT - 1) bbase[NBKT] = s[tid];
}

// bin edges into bucket-major staging: LDS bins + bulk reservation + coalesced flush
__global__ __launch_bounds__(256) void k_scat1(const int* __restrict__ src,
                                               const int* __restrict__ dst,
                                               const float* __restrict__ val,
                                               int* __restrict__ bcur,
                                               int2* __restrict__ staging) {
    __shared__ int2 bins[NBKT][CAP];      // 196*40*8 = 62.7 KB
    __shared__ int bincnt[NBKT];
    __shared__ int binbase[NBKT];
    const int tid = threadIdx.x;
    for (int b = tid; b < NBKT; b += 256) bincnt[b] = 0;
    __syncthreads();

    const int base = blockIdx.x * CHUNK1;
    const int end  = min(base + CHUNK1, EDGES);
    for (int e = base + tid; e < end; e += 256) {
        int d = dst[e];
        int b = d >> BKT_SH;
        int2 cv = make_int2(src[e] | ((d & (BKT_W - 1)) << 17), __float_as_int(val[e]));
        int slot = atomicAdd(&bincnt[b], 1);
        if (slot < CAP) {
            bins[b][slot] = cv;
        } else {                          // rare tail: direct append
            int p = atomicAdd(&bcur[b], 1);
            staging[p] = cv;
        }
    }
    __syncthreads();

    if (tid < NBKT) {                     // parallel bulk reservations
        int n = min(bincnt[tid], CAP);
        bincnt[tid]  = n;
        binbase[tid] = atomicAdd(&bcur[tid], n);
    }
    __syncthreads();

    const int wid = tid >> 6, lane = tid & 63;
    for (int b = wid; b < NBKT; b += 4) { // coalesced flush
        int n = bincnt[b], bb = binbase[b];
        for (int i = lane; i < n; i += 64)
            staging[bb + i] = bins[b][i];
    }
}

// ---------------- SPMM via bucket-local LDS accumulator ---------------------
// One block per 256-node bucket; sequential staging read; per-record:
// coalesced 256B gather of in[src,:], LDS atomic accumulate into accum[dl,:].
template <bool RELU>
__global__ __launch_bounds__(512) void k_spmm(const float* __restrict__ in,
                                              const int* __restrict__ bbase,
                                              const int2* __restrict__ staging,
                                              const float* __restrict__ bias,
                                              float* __restrict__ out) {
    __shared__ float accum[BKT_W * NHID];   // 64 KB
    const int tid  = threadIdx.x;
    const int lane = tid & 63;
    const int wv   = tid >> 6;              // 8 waves

    for (int i = tid; i < BKT_W * NHID; i += 512) accum[i] = 0.f;
    __syncthreads();

    const int beg = bbase[blockIdx.x];
    const int end = bbase[blockIdx.x + 1];

    int i = beg + wv;
    for (; i + 24 < end; i += 32) {         // 4-deep unroll across stride-8
        int2 c0 = staging[i];
        int2 c1 = staging[i + 8];
        int2 c2 = staging[i + 16];
        int2 c3 = staging[i + 24];
        float g0 = in[(c0.x & 0x1FFFF) * NHID + lane];
        float g1 = in[(c1.x & 0x1FFFF) * NHID + lane];
        float g2 = in[(c2.x & 0x1FFFF) * NHID + lane];
        float g3 = in[(c3.x & 0x1FFFF) * NHID + lane];
        atomicAdd(&accum[(c0.x >> 17) * NHID + lane], __int_as_float(c0.y) * g0);
        atomicAdd(&accum[(c1.x >> 17) * NHID + lane], __int_as_float(c1.y) * g1);
        atomicAdd(&accum[(c2.x >> 17) * NHID + lane], __int_as_float(c2.y) * g2);
        atomicAdd(&accum[(c3.x >> 17) * NHID + lane], __int_as_float(c3.y) * g3);
    }
    for (; i < end; i += 8) {
        int2 c = staging[i];
        float g = in[(c.x & 0x1FFFF) * NHID + lane];
        atomicAdd(&accum[(c.x >> 17) * NHID + lane], __int_as_float(c.y) * g);
    }
    __syncthreads();

    const int nb = blockIdx.x << BKT_SH;
    for (int f4 = tid; f4 < BKT_W * NHID / 4; f4 += 512) {
        int f   = f4 * 4;
        int row = f >> 6;
        int col = f & 63;
        int node = nb + row;
        if (node >= NN) break;
        float4 a = *(float4*)&accum[f];
        if (RELU) {
            a.x = fmaxf(a.x + bias[col + 0], 0.f);
            a.y = fmaxf(a.y + bias[col + 1], 0.f);
            a.z = fmaxf(a.z + bias[col + 2], 0.f);
            a.w = fmaxf(a.w + bias[col + 3], 0.f);
        }
        *(float4*)&out[(size_t)node * NHID + col] = a;
    }
}

// ---------------- Fused epilogue: heads + reparam + log_softmax -------------
__global__ __launch_bounds__(256) void k_final(const float* __restrict__ g2,
                                               const float* __restrict__ W11,
                                               const float* __restrict__ b11,
                                               const float* __restrict__ W12,
                                               const float* __restrict__ b12,
                                               const float* __restrict__ eps,
                                               float* __restrict__ out) {
    __shared__ float W11l[NHID * NCLASS];
    __shared__ float W12l[NHID * NCLASS];
    __shared__ float bl[2 * NCLASS];
    for (int i = threadIdx.x; i < NHID * NCLASS; i += 256) {
        W11l[i] = W11[i];
        W12l[i] = W12[i];
    }
    if (threadIdx.x < NCLASS) bl[threadIdx.x] = b11[threadIdx.x];
    else if (threadIdx.x < 2 * NCLASS) bl[threadIdx.x] = b12[threadIdx.x - NCLASS];
    __syncthreads();

    const int lane = threadIdx.x & 63;
    const int gw   = (blockIdx.x * 256 + threadIdx.x) >> 6;
    const bool act = lane < NCLASS;
    const int  cc  = act ? lane : NCLASS - 1;

    const int r0 = gw * 4;
    if (r0 >= NN) return;
    const int ur = __builtin_amdgcn_readfirstlane(r0);
    const float* __restrict__ g = g2 + (size_t)ur * NHID;

    float m[4], lg[4];
    #pragma unroll
    for (int i = 0; i < 4; ++i) { m[i] = bl[cc]; lg[i] = bl[NCLASS + cc]; }

    #pragma unroll 4
    for (int k = 0; k < NHID; ++k) {
        float w1 = W11l[k * NCLASS + cc];
        float w2 = W12l[k * NCLASS + cc];
        float ga = g[k], gb = g[NHID + k], gc = g[2 * NHID + k], gd = g[3 * NHID + k];
        m[0] += ga * w1; lg[0] += ga * w2;
        m[1] += gb * w1; lg[1] += gb * w2;
        m[2] += gc * w1; lg[2] += gc * w2;
        m[3] += gd * w1; lg[3] += gd * w2;
    }

    float z[4];
    #pragma unroll
    for (int i = 0; i < 4; ++i)
        z[i] = act ? (eps[(size_t)(ur + i) * NCLASS + lane] * expf(lg[i]) + m[i]) : -1e30f;

    float zmax[4], s[4];
    #pragma unroll
    for (int i = 0; i < 4; ++i) zmax[i] = z[i];
    #pragma unroll
    for (int off = 32; off >= 1; off >>= 1) {
        #pragma unroll
        for (int i = 0; i < 4; ++i) zmax[i] = fmaxf(zmax[i], __shfl_xor(zmax[i], off));
    }
    #pragma unroll
    for (int i = 0; i < 4; ++i) s[i] = act ? expf(z[i] - zmax[i]) : 0.f;
    #pragma unroll
    for (int off = 32; off >= 1; off >>= 1) {
        #pragma unroll
        for (int i = 0; i < 4; ++i) s[i] += __shfl_xor(s[i], off);
    }
    if (act) {
        #pragma unroll
        for (int i = 0; i < 4; ++i)
            out[(size_t)(ur + i) * NCLASS + lane] = z[i] - zmax[i] - logf(s[i]);
    }
}

// ---------------- launcher --------------------------------------------------
extern "C" void kernel_launch(void* const* d_in, const int* in_sizes, int n_in,
                              void* d_out, int out_size, void* d_ws, size_t ws_size,
                              hipStream_t stream) {
    const float* x        = (const float*)d_in[0];
    const int*   edge_src = (const int*)d_in[1];
    const int*   edge_dst = (const int*)d_in[2];
    const float* edge_val = (const float*)d_in[3];
    const float* eps      = (const float*)d_in[4];
    const float* W1       = (const float*)d_in[5];
    const float* b1       = (const float*)d_in[6];
    const float* W11      = (const float*)d_in[7];
    const float* b11      = (const float*)d_in[8];
    const float* W12      = (const float*)d_in[9];
    const float* b12      = (const float*)d_in[10];
    float* out = (float*)d_out;

    // ws layout (no aliasing: staging is reused by BOTH spmm passes)
    int2*  staging = (int2*)d_ws;                  // EDGES * 8B
    float* xw      = (float*)(staging + EDGES);    // NN*64
    float* h       = xw + (size_t)NN * NHID;       // NN*64
    int*   bcnt    = (int*)(h + (size_t)NN * NHID);// NBKT
    int*   bbase   = bcnt + NBKT;                  // NBKT+1
    int*   bcur    = bbase + NBKT + 1;             // NBKT
    float* g2 = xw;                                // xw dead after spmmA

    k_gemm1<<<(NN + BM - 1) / BM, 256, 0, stream>>>(x, W1, xw);
    k_zero0<<<1, 256, 0, stream>>>(bcnt);
    k_bhist<<<(EDGES / 4 + 255) / 256, 256, 0, stream>>>(edge_dst, bcnt);
    k_bscan<<<1, 256, 0, stream>>>(bcnt, bbase, bcur);
    k_scat1<<<NBLK1, 256, 0, stream>>>(edge_src, edge_dst, edge_val, bcur, staging);
    k_spmm<true><<<NBKT, 512, 0, stream>>>(xw, bbase, staging, b1, h);
    k_spmm<false><<<NBKT, 512, 0, stream>>>(h, bbase, staging, nullptr, g2);
    k_final<<<(NN / 4 + 3) / 4, 256, 0, stream>>>(g2, W11, b11, W12, b12, eps, out);
}